// Round 1
// baseline (109660.815 us; speedup 1.0000x reference)
//
#include <hip/hip_runtime.h>
#include <hip/hip_bf16.h>
#include <cstdint>
#include <cstddef>

// ---------------------------------------------------------------------------
// FlumenHead: encoder MLP (32->512->512->1024) + 2048-step LSTM (D=9, F=1024)
// Strategy: persistent cooperative-by-construction kernel (32 WGs x 512 thr,
// guaranteed co-resident), per-step producer/consumer flags via agent-scope
// relaxed atomics (sc1, LLC-coherent), bf16 MFMA 16x16x32 with gates mapped to
// M so the whole cell update is lane-local (no LDS, no barriers in main loop).
// ---------------------------------------------------------------------------

typedef __bf16 bf16x8_t __attribute__((ext_vector_type(8)));
typedef float f32x4_t __attribute__((ext_vector_type(4)));
typedef unsigned long long u64_t;
typedef unsigned long long u64x2_t __attribute__((ext_vector_type(2)));
typedef unsigned short u16x4_t __attribute__((ext_vector_type(4)));

// workspace layout (bytes); total ~17.8 MB
#define WS_FLAGS   0          // int  flags[2048][32]            256 KB
#define WS_HBUF    262144     // u16  hbuf[2][64][1024] bf16     256 KB
#define WS_WBF     524288     // u16  Wbf[4096][1024] bf16         8 MB
#define WS_WAUG    8912896    // u16  Waug[4096][32] bf16        256 KB
#define WS_XHAT    9175040    // u16  Xhat[64][2048][32] bf16      8 MB
#define WS_H1      17563648   // f32  h1[64][512]                128 KB
#define WS_H2      17694720   // f32  h2[64][512]                128 KB

__device__ __forceinline__ unsigned short f2bf(float f) {
  unsigned int u = __float_as_uint(f);
  u = (u + 0x7fffu + ((u >> 16) & 1u)) >> 16;   // RNE
  return (unsigned short)u;
}
__device__ __forceinline__ float sigm(float x) { return 1.f / (1.f + __expf(-x)); }
__device__ __forceinline__ float tanh_f(float x) {
  // overflow-safe tanh via exp(-2|x|)
  float e = __expf(-2.f * fabsf(x));
  float r = (1.f - e) / (1.f + e);
  return copysignf(r, x);
}

// ---------------------------- encoder ----------------------------

// layer1: [64,32] @ W0^T[32,512] + b0, relu -> h1[64,512]
__global__ void flumen_enc1(const float* __restrict__ x, const float* __restrict__ W,
                            const float* __restrict__ b, float* __restrict__ h1) {
  const int bb = blockIdx.x;   // batch 0..63
  const int o  = threadIdx.x;  // 0..511
  const f32x4_t* xr = (const f32x4_t*)(x + bb * 32);
  const f32x4_t* wr = (const f32x4_t*)(W + o * 32);
  float acc = b[o];
#pragma unroll
  for (int q = 0; q < 8; ++q) {
    f32x4_t xv = xr[q], wv = wr[q];
    acc += xv[0] * wv[0] + xv[1] * wv[1] + xv[2] * wv[2] + xv[3] * wv[3];
  }
  h1[bb * 512 + o] = fmaxf(acc, 0.f);
}

// layer2: [64,512] @ W1^T[512,512] + b1, relu -> h2. grid=8, block=512.
// Each block: 64 output features, 8 batches/thread, input staged in LDS.
__global__ void flumen_enc2(const float* __restrict__ in, const float* __restrict__ W,
                            const float* __restrict__ bv, float* __restrict__ outb) {
  __shared__ float s[64 * 256];  // 64 KB, half-K chunk
  const int tid = threadIdx.x;
  const int ol = tid & 63, bg = tid >> 6;
  const int o = blockIdx.x * 64 + ol;
  float bias = bv[o];
  float acc[8];
#pragma unroll
  for (int q = 0; q < 8; ++q) acc[q] = bias;
  for (int p = 0; p < 2; ++p) {
    __syncthreads();
    for (int i = tid; i < 4096; i += 512) {
      int flat = i * 4;
      int bb = flat >> 8, kk = flat & 255;
      *(f32x4_t*)(s + flat) = *(const f32x4_t*)(in + bb * 512 + p * 256 + kk);
    }
    __syncthreads();
    for (int kk = 0; kk < 256; kk += 4) {
      f32x4_t wv = *(const f32x4_t*)(W + o * 512 + p * 256 + kk);
#pragma unroll
      for (int j = 0; j < 4; ++j) {
        float wj = wv[j];
#pragma unroll
        for (int q = 0; q < 8; ++q)
          acc[q] += wj * s[(bg * 8 + q) * 256 + kk + j];
      }
    }
  }
#pragma unroll
  for (int q = 0; q < 8; ++q)
    outb[(bg * 8 + q) * 512 + o] = fmaxf(acc[q], 0.f);
}

// layer3: [64,512] @ W2^T[512,1024] + b2 (no relu) -> h0.
// Writes h_seq[:,0,:] (fp32 out) and hbuf[0] (bf16). grid=16, block=512.
__global__ void flumen_enc3(const float* __restrict__ in, const float* __restrict__ W,
                            const float* __restrict__ bv, float* __restrict__ dout,
                            unsigned short* __restrict__ hbuf) {
  __shared__ float s[64 * 256];
  const int tid = threadIdx.x;
  const int ol = tid & 63, bg = tid >> 6;
  const int o = blockIdx.x * 64 + ol;   // 0..1023
  float bias = bv[o];
  float acc[8];
#pragma unroll
  for (int q = 0; q < 8; ++q) acc[q] = bias;
  for (int p = 0; p < 2; ++p) {
    __syncthreads();
    for (int i = tid; i < 4096; i += 512) {
      int flat = i * 4;
      int bb = flat >> 8, kk = flat & 255;
      *(f32x4_t*)(s + flat) = *(const f32x4_t*)(in + bb * 512 + p * 256 + kk);
    }
    __syncthreads();
    for (int kk = 0; kk < 256; kk += 4) {
      f32x4_t wv = *(const f32x4_t*)(W + o * 512 + p * 256 + kk);
#pragma unroll
      for (int j = 0; j < 4; ++j) {
        float wj = wv[j];
#pragma unroll
        for (int q = 0; q < 8; ++q)
          acc[q] += wj * s[(bg * 8 + q) * 256 + kk + j];
      }
    }
  }
  float* out_hseq = dout + 65536;
#pragma unroll
  for (int q = 0; q < 8; ++q) {
    int bb = bg * 8 + q;
    float v = acc[q];
    out_hseq[(size_t)bb * 2097152 + o] = v;   // h_seq[b][0][o]
    hbuf[bb * 1024 + o] = f2bf(v);            // buffer 0
  }
}

// ---------------------------- precompute ----------------------------

// W_hh fp32 [4096][1024] -> bf16. grid=2048, block=512, 4 elems/thread.
__global__ void flumen_convw(const float* __restrict__ src, unsigned short* __restrict__ dst) {
  int i = (blockIdx.x * 512 + threadIdx.x) * 4;
  f32x4_t v = *(const f32x4_t*)(src + i);
  u16x4_t o;
#pragma unroll
  for (int j = 0; j < 4; ++j) o[j] = f2bf(v[j]);
  *(u16x4_t*)(dst + i) = o;
}

// Waug[r][0..8]=W_ih[r], [9]=bias[r], rest 0. grid=64.
__global__ void flumen_convaug(const float* __restrict__ wih, const float* __restrict__ bias,
                               unsigned short* __restrict__ dst) {
  int i = (blockIdx.x * 512 + threadIdx.x) * 4;
  int row = i >> 5, c0 = i & 31;
  u16x4_t o;
#pragma unroll
  for (int j = 0; j < 4; ++j) {
    int cc = c0 + j;
    float v = (cc < 9) ? wih[row * 9 + cc] : (cc == 9 ? bias[row] : 0.f);
    o[j] = f2bf(v);
  }
  *(u16x4_t*)(dst + i) = o;
}

// Xhat[b][t][0..8]=x, [9]=1.0, rest 0. grid=2048.
__global__ void flumen_convx(const float* __restrict__ xin, unsigned short* __restrict__ dst) {
  int i = (blockIdx.x * 512 + threadIdx.x) * 4;
  int row = i >> 5, c0 = i & 31;   // row = b*2048+t
  u16x4_t o;
#pragma unroll
  for (int j = 0; j < 4; ++j) {
    int cc = c0 + j;
    float v = (cc < 9) ? xin[row * 9 + cc] : (cc == 9 ? 1.f : 0.f);
    o[j] = f2bf(v);
  }
  *(u16x4_t*)(dst + i) = o;
}

// ---------------------------- persistent LSTM ----------------------------
// 32 WGs (1/CU guaranteed co-resident), 8 waves each.
// WG w owns features [32w,32w+32). Wave = hh*4+n: hh picks 16-feature half,
// n picks 16-batch N-tile. A = W rows (M-tiles = gates i,f,g,o), B = h^T.
// C layout (m89): col=lane&15 -> batch, row=4*(lane>>4)+j -> feature quad,
// so each lane owns all 4 gates of one (batch, feature-quad): lane-local cell.
__global__ __launch_bounds__(512, 2) void flumen_lstm(
    const unsigned short* __restrict__ Wbf,
    const unsigned short* __restrict__ Waug,
    const unsigned short* __restrict__ Xhat,
    unsigned short* hbuf, int* flags, float* out)
{
  float* out_hlast = out;
  float* out_hseq  = out + 65536;
  const int w    = blockIdx.x;       // 0..31
  const int tid  = threadIdx.x;
  const int lane = tid & 63;
  const int wave = tid >> 6;         // 0..7
  const int hh   = wave >> 2;        // feature half of WG's 32
  const int n    = wave & 3;         // batch tile
  const int l15  = lane & 15;
  const int l4   = lane >> 4;
  const int batch = n * 16 + l15;
  const int wr   = w * 32 + hh * 16 + l15;     // A-frag feature row
  const int fq   = w * 32 + hh * 16 + l4 * 4;  // C feature-quad base

  int aoff[4], agoff[4];
#pragma unroll
  for (int g = 0; g < 4; ++g) {
    aoff[g]  = (g * 1024 + wr) * 1024 + l4 * 8;  // Wbf ushort offset
    agoff[g] = (g * 1024 + wr) * 32   + l4 * 8;  // Waug ushort offset
  }
  const u64_t* hb64 = (const u64_t*)hbuf;
  u64_t* hb64w = (u64_t*)hbuf;

  float carr[4] = {0.f, 0.f, 0.f, 0.f};

  for (int t = 0; t < 2048; ++t) {
    if (t > 0) {
      // wait for all 32 WGs to have published h_t (8 waves each -> ==8)
      const int* fp = flags + (t - 1) * 32 + (lane & 31);
      int v, iter = 0;
      do {
        v = __hip_atomic_load(fp, __ATOMIC_RELAXED, __HIP_MEMORY_SCOPE_AGENT);
      } while (__any(v != 8) && ++iter < (1 << 20));  // bounded: no hang on protocol bug
      asm volatile("" ::: "memory");
    }
    const int buf = t & 1;
    f32x4_t acc[4];
#pragma unroll
    for (int g = 0; g < 4; ++g) acc[g] = (f32x4_t){0.f, 0.f, 0.f, 0.f};

    const int bidx = buf * 16384 + batch * 256 + l4 * 2;  // u64 index into hbuf
#pragma unroll 4
    for (int kt = 0; kt < 32; ++kt) {
      u64x2_t q;
      q.x = __hip_atomic_load(hb64 + bidx + kt * 8,     __ATOMIC_RELAXED, __HIP_MEMORY_SCOPE_AGENT);
      q.y = __hip_atomic_load(hb64 + bidx + kt * 8 + 1, __ATOMIC_RELAXED, __HIP_MEMORY_SCOPE_AGENT);
      bf16x8_t bfrag = __builtin_bit_cast(bf16x8_t, q);
#pragma unroll
      for (int g = 0; g < 4; ++g) {
        bf16x8_t af = *(const bf16x8_t*)(Wbf + aoff[g] + kt * 32);
        acc[g] = __builtin_amdgcn_mfma_f32_16x16x32_bf16(af, bfrag, acc[g], 0, 0, 0);
      }
    }
    {  // augmented K-tile: x-term + bias
      bf16x8_t bfrag = *(const bf16x8_t*)(Xhat + (batch * 2048 + t) * 32 + l4 * 8);
#pragma unroll
      for (int g = 0; g < 4; ++g) {
        bf16x8_t af = *(const bf16x8_t*)(Waug + agoff[g]);
        acc[g] = __builtin_amdgcn_mfma_f32_16x16x32_bf16(af, bfrag, acc[g], 0, 0, 0);
      }
    }

    f32x4_t hval;
#pragma unroll
    for (int j = 0; j < 4; ++j) {
      float iv = acc[0][j], fv = acc[1][j], gv = acc[2][j], ov = acc[3][j];
      carr[j] = sigm(fv) * carr[j] + sigm(iv) * tanh_f(gv);
      hval[j] = sigm(ov) * tanh_f(carr[j]);
    }

    if (t < 2047) {
      // h_seq emits PRE-step h: step t produces h_{t+1} -> h_seq[:, t+1, :]
      *(f32x4_t*)(out_hseq + ((size_t)batch * 2048 + (size_t)(t + 1)) * 1024 + fq) = hval;
      u64_t packed = (u64_t)f2bf(hval[0]) | ((u64_t)f2bf(hval[1]) << 16)
                   | ((u64_t)f2bf(hval[2]) << 32) | ((u64_t)f2bf(hval[3]) << 48);
      __hip_atomic_store(hb64w + ((buf ^ 1) * 16384 + batch * 256 + (fq >> 2)), packed,
                         __ATOMIC_RELAXED, __HIP_MEMORY_SCOPE_AGENT);
      asm volatile("s_waitcnt vmcnt(0)" ::: "memory");  // publish before flag
      if (lane == 0)
        __hip_atomic_fetch_add(flags + t * 32 + w, 1, __ATOMIC_RELAXED, __HIP_MEMORY_SCOPE_AGENT);
    } else {
      *(f32x4_t*)(out_hlast + batch * 1024 + fq) = hval;  // h_last = h_2048
    }
  }
}

// ---------------------------- launch ----------------------------

extern "C" void kernel_launch(void* const* d_in, const int* in_sizes, int n_in,
                              void* d_out, int out_size, void* d_ws, size_t ws_size,
                              hipStream_t stream) {
  const float* initial_state = (const float*)d_in[0];
  const float* rnn_input     = (const float*)d_in[1];
  const float* enc_w0        = (const float*)d_in[2];
  const float* enc_b0        = (const float*)d_in[3];
  const float* enc_w1        = (const float*)d_in[4];
  const float* enc_b1        = (const float*)d_in[5];
  const float* enc_w2        = (const float*)d_in[6];
  const float* enc_b2        = (const float*)d_in[7];
  const float* w_ih          = (const float*)d_in[8];
  const float* w_hh          = (const float*)d_in[9];
  const float* bias          = (const float*)d_in[10];

  char* ws = (char*)d_ws;
  int*            flags = (int*)(ws + WS_FLAGS);
  unsigned short* hbuf  = (unsigned short*)(ws + WS_HBUF);
  unsigned short* Wbf   = (unsigned short*)(ws + WS_WBF);
  unsigned short* Waug  = (unsigned short*)(ws + WS_WAUG);
  unsigned short* Xhat  = (unsigned short*)(ws + WS_XHAT);
  float*          h1    = (float*)(ws + WS_H1);
  float*          h2    = (float*)(ws + WS_H2);
  float*          out   = (float*)d_out;

  hipMemsetAsync(flags, 0, 2048 * 32 * 4, stream);
  flumen_enc1<<<64, 512, 0, stream>>>(initial_state, enc_w0, enc_b0, h1);
  flumen_enc2<<<8, 512, 0, stream>>>(h1, enc_w1, enc_b1, h2);
  flumen_enc3<<<16, 512, 0, stream>>>(h2, enc_w2, enc_b2, out, hbuf);
  flumen_convw<<<2048, 512, 0, stream>>>(w_hh, Wbf);
  flumen_convaug<<<64, 512, 0, stream>>>(w_ih, bias, Waug);
  flumen_convx<<<2048, 512, 0, stream>>>(rnn_input, Xhat);
  flumen_lstm<<<32, 512, 0, stream>>>(Wbf, Waug, Xhat, hbuf, flags, out);
}

// Round 2
// 28651.044 us; speedup vs baseline: 3.8275x; 3.8275x over previous
//
#include <hip/hip_runtime.h>
#include <hip/hip_bf16.h>
#include <cstdint>
#include <cstddef>

// ---------------------------------------------------------------------------
// FlumenHead: encoder MLP (32->512->512->1024) + 2048-step LSTM (D=9, F=1024)
// v2: persistent 32-WG kernel; h broadcast via coalesced sc1 fill into
// XOR-swizzled LDS; fragment-shuffled W for coalesced A-loads; LDS-staged
// publish (64B-contiguous sc1 stores) + single flag/step; h_seq full-line
// writes off the critical path.
// ---------------------------------------------------------------------------

typedef __bf16 bf16x8_t __attribute__((ext_vector_type(8)));
typedef float f32x4_t __attribute__((ext_vector_type(4)));
typedef unsigned long long u64_t;
typedef unsigned long long u64x2_t __attribute__((ext_vector_type(2)));
typedef unsigned short u16x4_t __attribute__((ext_vector_type(4)));

// workspace layout (bytes); total ~17.8 MB
#define WS_FLAGS   0          // int  flags[2048][32] (128B stride/step)  256 KB
#define WS_HBUF    262144     // u16  hbuf[2][64][1024] bf16              256 KB
#define WS_WSHUF   524288     // u16  Wshuf[256 mt][32 kt][64 lane][8]      8 MB
#define WS_WAUG    8912896    // u16  Waug[4096][32] bf16                 256 KB
#define WS_XHAT    9175040    // u16  Xhat[2048 t][64 b][32] bf16           8 MB
#define WS_H1      17563648   // f32  h1[64][512]                         128 KB
#define WS_H2      17694720   // f32  h2[64][512]                         128 KB

#define FLAG_TARGET 128       // 32 WGs x 4 publishing waves

__device__ __forceinline__ unsigned short f2bf(float f) {
  unsigned int u = __float_as_uint(f);
  u = (u + 0x7fffu + ((u >> 16) & 1u)) >> 16;   // RNE
  return (unsigned short)u;
}
__device__ __forceinline__ float sigm(float x) { return 1.f / (1.f + __expf(-x)); }
__device__ __forceinline__ float tanh_f(float x) {
  float e = __expf(-2.f * fabsf(x));
  float r = (1.f - e) / (1.f + e);
  return copysignf(r, x);
}

// ---------------------------- encoder ----------------------------

__global__ void flumen_enc1(const float* __restrict__ x, const float* __restrict__ W,
                            const float* __restrict__ b, float* __restrict__ h1) {
  const int bb = blockIdx.x;   // batch 0..63
  const int o  = threadIdx.x;  // 0..511
  const f32x4_t* xr = (const f32x4_t*)(x + bb * 32);
  const f32x4_t* wr = (const f32x4_t*)(W + o * 32);
  float acc = b[o];
#pragma unroll
  for (int q = 0; q < 8; ++q) {
    f32x4_t xv = xr[q], wv = wr[q];
    acc += xv[0] * wv[0] + xv[1] * wv[1] + xv[2] * wv[2] + xv[3] * wv[3];
  }
  h1[bb * 512 + o] = fmaxf(acc, 0.f);
}

__global__ void flumen_enc2(const float* __restrict__ in, const float* __restrict__ W,
                            const float* __restrict__ bv, float* __restrict__ outb) {
  __shared__ float s[64 * 256];
  const int tid = threadIdx.x;
  const int ol = tid & 63, bg = tid >> 6;
  const int o = blockIdx.x * 64 + ol;
  float bias = bv[o];
  float acc[8];
#pragma unroll
  for (int q = 0; q < 8; ++q) acc[q] = bias;
  for (int p = 0; p < 2; ++p) {
    __syncthreads();
    for (int i = tid; i < 4096; i += 512) {
      int flat = i * 4;
      int bb = flat >> 8, kk = flat & 255;
      *(f32x4_t*)(s + flat) = *(const f32x4_t*)(in + bb * 512 + p * 256 + kk);
    }
    __syncthreads();
    for (int kk = 0; kk < 256; kk += 4) {
      f32x4_t wv = *(const f32x4_t*)(W + o * 512 + p * 256 + kk);
#pragma unroll
      for (int j = 0; j < 4; ++j) {
        float wj = wv[j];
#pragma unroll
        for (int q = 0; q < 8; ++q)
          acc[q] += wj * s[(bg * 8 + q) * 256 + kk + j];
      }
    }
  }
#pragma unroll
  for (int q = 0; q < 8; ++q)
    outb[(bg * 8 + q) * 512 + o] = fmaxf(acc[q], 0.f);
}

__global__ void flumen_enc3(const float* __restrict__ in, const float* __restrict__ W,
                            const float* __restrict__ bv, float* __restrict__ dout,
                            unsigned short* __restrict__ hbuf) {
  __shared__ float s[64 * 256];
  const int tid = threadIdx.x;
  const int ol = tid & 63, bg = tid >> 6;
  const int o = blockIdx.x * 64 + ol;   // 0..1023
  float bias = bv[o];
  float acc[8];
#pragma unroll
  for (int q = 0; q < 8; ++q) acc[q] = bias;
  for (int p = 0; p < 2; ++p) {
    __syncthreads();
    for (int i = tid; i < 4096; i += 512) {
      int flat = i * 4;
      int bb = flat >> 8, kk = flat & 255;
      *(f32x4_t*)(s + flat) = *(const f32x4_t*)(in + bb * 512 + p * 256 + kk);
    }
    __syncthreads();
    for (int kk = 0; kk < 256; kk += 4) {
      f32x4_t wv = *(const f32x4_t*)(W + o * 512 + p * 256 + kk);
#pragma unroll
      for (int j = 0; j < 4; ++j) {
        float wj = wv[j];
#pragma unroll
        for (int q = 0; q < 8; ++q)
          acc[q] += wj * s[(bg * 8 + q) * 256 + kk + j];
      }
    }
  }
  float* out_hseq = dout + 65536;
#pragma unroll
  for (int q = 0; q < 8; ++q) {
    int bb = bg * 8 + q;
    float v = acc[q];
    out_hseq[(size_t)bb * 2097152 + o] = v;   // h_seq[b][0][o]
    hbuf[bb * 1024 + o] = f2bf(v);            // buffer 0
  }
}

// ---------------------------- precompute ----------------------------

// W_hh -> MFMA-fragment-contiguous order:
// Wshuf[((mt*32+kt)*64+lane)*8 + e] = W[(g*1024 + fb*16 + (lane&15))*1024
//                                       + kt*32 + (lane>>4)*8 + e],
// mt = g*64+fb. One thread per (mt,kt,lane). grid=1024, block=512.
__global__ void flumen_wshuf(const float* __restrict__ src, unsigned short* __restrict__ dst) {
  int idx = blockIdx.x * 512 + threadIdx.x;      // 0..524287
  int lane = idx & 63, kt = (idx >> 6) & 31, mt = idx >> 11;
  int g = mt >> 6, fb = mt & 63;
  int r = g * 1024 + fb * 16 + (lane & 15);
  int k0 = kt * 32 + (lane >> 4) * 8;
  const float* sp = src + (size_t)r * 1024 + k0;
  f32x4_t v0 = *(const f32x4_t*)(sp);
  f32x4_t v1 = *(const f32x4_t*)(sp + 4);
  u16x4_t o0, o1;
#pragma unroll
  for (int j = 0; j < 4; ++j) { o0[j] = f2bf(v0[j]); o1[j] = f2bf(v1[j]); }
  u16x4_t* dp = (u16x4_t*)(dst + (size_t)idx * 8);
  dp[0] = o0; dp[1] = o1;
}

// Waug[r][0..8]=W_ih[r], [9]=bias[r], rest 0. grid=64.
__global__ void flumen_convaug(const float* __restrict__ wih, const float* __restrict__ bias,
                               unsigned short* __restrict__ dst) {
  int i = (blockIdx.x * 512 + threadIdx.x) * 4;
  int row = i >> 5, c0 = i & 31;
  u16x4_t o;
#pragma unroll
  for (int j = 0; j < 4; ++j) {
    int cc = c0 + j;
    float v = (cc < 9) ? wih[row * 9 + cc] : (cc == 9 ? bias[row] : 0.f);
    o[j] = f2bf(v);
  }
  *(u16x4_t*)(dst + i) = o;
}

// Xhat[t][b][0..8]=x[b][t][:], [9]=1.0, rest 0. grid=2048.
__global__ void flumen_convx(const float* __restrict__ xin, unsigned short* __restrict__ dst) {
  int i = (blockIdx.x * 512 + threadIdx.x) * 4;   // elem index, 4 at a time
  int b = i >> 16, t = (i >> 5) & 2047, c0 = i & 31;
  u16x4_t o;
#pragma unroll
  for (int j = 0; j < 4; ++j) {
    int cc = c0 + j;
    float v = (cc < 9) ? xin[((size_t)b * 2048 + t) * 9 + cc] : (cc == 9 ? 1.f : 0.f);
    o[j] = f2bf(v);
  }
  *(u16x4_t*)(dst + ((size_t)t * 64 + b) * 32 + c0) = o;
}

// ---------------------------- persistent LSTM ----------------------------
// 32 WGs x 512 thr. WG w owns features [32w,32w+32). Wave = hh*4+n.
// Per step: coalesced sc1 fill of h into swizzled LDS; 33 MFMA K-tiles per
// gate; lane-local cell update; LDS-staged publish + h_seq.
__global__ __launch_bounds__(512, 2) void flumen_lstm(
    const unsigned short* __restrict__ Wshuf,
    const unsigned short* __restrict__ Waug,
    const unsigned short* __restrict__ Xhat,
    unsigned short* hbuf, int* flags, float* out)
{
  __shared__ __align__(16) char smem[140288];   // 128K h_lds + 9216 staging
  char*  h_lds = smem;                           // [64][2048B] swizzled bf16
  float* hs    = (float*)(smem + 131072);        // [64][36] f32 staging

  float* out_hlast = out;
  float* out_hseq  = out + 65536;
  const int w    = blockIdx.x;       // 0..31
  const int tid  = threadIdx.x;
  const int lane = tid & 63;
  const int wave = tid >> 6;         // 0..7
  const int hh   = wave >> 2;
  const int n    = wave & 3;
  const int l15  = lane & 15;
  const int l4   = lane >> 4;
  const int batch = n * 16 + l15;
  const int fb   = w * 2 + hh;                 // 16-feature block 0..63
  const int fq   = w * 32 + hh * 16 + l4 * 4;  // C feature-quad base
  const int bsw  = (batch & 7) << 4;           // LDS swizzle for B-frags
  const int brow = batch * 2048;

  // A-frag byte bases per gate (add kt*1024 per K-tile)
  size_t abase[4];
#pragma unroll
  for (int g = 0; g < 4; ++g)
    abase[g] = ((size_t)((g * 64 + fb) * 32) << 10) + lane * 16;

  // Waug frags: constant over t -> hoist
  bf16x8_t wfrag[4];
#pragma unroll
  for (int g = 0; g < 4; ++g) {
    int row = g * 1024 + fb * 16 + l15;
    wfrag[g] = *(const bf16x8_t*)(Waug + row * 32 + l4 * 8);
  }

  float carr[4] = {0.f, 0.f, 0.f, 0.f};

  for (int t = 0; t < 2048; ++t) {
    // Xhat frag early (independent of h_t; hides under poll+fill)
    bf16x8_t xf = *(const bf16x8_t*)(Xhat + ((size_t)t * 64 + batch) * 32 + l4 * 8);

    if (t > 0) {
      const int* fp = flags + (t - 1) * 32;
      int iter = 0;
      while (__hip_atomic_load(fp, __ATOMIC_RELAXED, __HIP_MEMORY_SCOPE_AGENT) < FLAG_TARGET
             && ++iter < (1 << 20)) {}
      asm volatile("" ::: "memory");
    }

    // cooperative coalesced sc1 fill: hbuf[t&1] -> swizzled LDS (128 KB)
    {
      const char* src = (const char*)hbuf + (size_t)(t & 1) * 131072 + tid * 16;
      f32x4_t v[16];
#pragma unroll
      for (int i = 0; i < 16; ++i) {
        const char* p = src + i * 8192;
        asm volatile("global_load_dwordx4 %0, %1, off sc1" : "=v"(v[i]) : "v"(p) : "memory");
      }
      asm volatile("s_waitcnt vmcnt(0)" ::: "memory");
      __builtin_amdgcn_sched_barrier(0);
#pragma unroll
      for (int i = 0; i < 16; ++i) {
        int goff = i * 8192 + tid * 16;
        int b = goff >> 11, o = goff & 2047;
        *(f32x4_t*)(h_lds + b * 2048 + (o ^ ((b & 7) << 4))) = v[i];
      }
    }
    __syncthreads();

    // augmented K-tile first (x-term + bias)
    f32x4_t acc[4];
#pragma unroll
    for (int g = 0; g < 4; ++g)
      acc[g] = __builtin_amdgcn_mfma_f32_16x16x32_bf16(wfrag[g], xf,
                                                       (f32x4_t){0.f,0.f,0.f,0.f}, 0, 0, 0);
    // main K loop
#pragma unroll 4
    for (int kt = 0; kt < 32; ++kt) {
      bf16x8_t bfrag = *(const bf16x8_t*)(h_lds + brow + ((kt * 64 + l4 * 16) ^ bsw));
#pragma unroll
      for (int g = 0; g < 4; ++g) {
        bf16x8_t af = *(const bf16x8_t*)((const char*)Wshuf + abase[g] + ((size_t)kt << 10));
        acc[g] = __builtin_amdgcn_mfma_f32_16x16x32_bf16(af, bfrag, acc[g], 0, 0, 0);
      }
    }

    // lane-local cell update
    f32x4_t hval;
#pragma unroll
    for (int j = 0; j < 4; ++j) {
      float iv = acc[0][j], fv = acc[1][j], gv = acc[2][j], ov = acc[3][j];
      carr[j] = sigm(fv) * carr[j] + sigm(iv) * tanh_f(gv);
      hval[j] = sigm(ov) * tanh_f(carr[j]);
    }

    if (t < 2047) {
      // stage h_{t+1} in LDS: hs[batch][feat_in_wg]
      *(f32x4_t*)(hs + batch * 36 + hh * 16 + l4 * 4) = hval;
      __syncthreads();
      int b = (wave & 3) * 16 + (lane >> 2);
      int seg = lane & 3;
      f32x4_t u0 = *(f32x4_t*)(hs + b * 36 + seg * 8);
      f32x4_t u1 = *(f32x4_t*)(hs + b * 36 + seg * 8 + 4);
      if (wave < 4) {
        // publish: 16B bf16 chunk, 64B-contiguous rows; then flag
        u64_t lo = (u64_t)f2bf(u0[0]) | ((u64_t)f2bf(u0[1]) << 16)
                 | ((u64_t)f2bf(u0[2]) << 32) | ((u64_t)f2bf(u0[3]) << 48);
        u64_t hi = (u64_t)f2bf(u1[0]) | ((u64_t)f2bf(u1[1]) << 16)
                 | ((u64_t)f2bf(u1[2]) << 32) | ((u64_t)f2bf(u1[3]) << 48);
        u64x2_t q = {lo, hi};
        char* dst = (char*)hbuf + (size_t)((t + 1) & 1) * 131072 + b * 2048 + w * 64 + seg * 16;
        asm volatile("global_store_dwordx4 %0, %1, off sc1" :: "v"(dst), "v"(q) : "memory");
        asm volatile("s_waitcnt vmcnt(0)" ::: "memory");
        if (lane == 0)
          __hip_atomic_fetch_add(flags + t * 32, 1, __ATOMIC_RELAXED, __HIP_MEMORY_SCOPE_AGENT);
      } else {
        // h_seq[:, t+1, :]: full-line f32 writes, off critical path
        float* dst = out_hseq + ((size_t)b * 2048 + (size_t)(t + 1)) * 1024 + w * 32 + seg * 8;
        *(f32x4_t*)(dst)     = u0;
        *(f32x4_t*)(dst + 4) = u1;
      }
    } else {
      *(f32x4_t*)(out_hlast + batch * 1024 + fq) = hval;  // h_last = h_2048
    }
  }
}

// ---------------------------- launch ----------------------------

extern "C" void kernel_launch(void* const* d_in, const int* in_sizes, int n_in,
                              void* d_out, int out_size, void* d_ws, size_t ws_size,
                              hipStream_t stream) {
  const float* initial_state = (const float*)d_in[0];
  const float* rnn_input     = (const float*)d_in[1];
  const float* enc_w0        = (const float*)d_in[2];
  const float* enc_b0        = (const float*)d_in[3];
  const float* enc_w1        = (const float*)d_in[4];
  const float* enc_b1        = (const float*)d_in[5];
  const float* enc_w2        = (const float*)d_in[6];
  const float* enc_b2        = (const float*)d_in[7];
  const float* w_ih          = (const float*)d_in[8];
  const float* w_hh          = (const float*)d_in[9];
  const float* bias          = (const float*)d_in[10];

  char* ws = (char*)d_ws;
  int*            flags = (int*)(ws + WS_FLAGS);
  unsigned short* hbuf  = (unsigned short*)(ws + WS_HBUF);
  unsigned short* Wshuf = (unsigned short*)(ws + WS_WSHUF);
  unsigned short* Waug  = (unsigned short*)(ws + WS_WAUG);
  unsigned short* Xhat  = (unsigned short*)(ws + WS_XHAT);
  float*          h1    = (float*)(ws + WS_H1);
  float*          h2    = (float*)(ws + WS_H2);
  float*          out   = (float*)d_out;

  hipMemsetAsync(flags, 0, 262144, stream);
  flumen_enc1<<<64, 512, 0, stream>>>(initial_state, enc_w0, enc_b0, h1);
  flumen_enc2<<<8, 512, 0, stream>>>(h1, enc_w1, enc_b1, h2);
  flumen_enc3<<<16, 512, 0, stream>>>(h2, enc_w2, enc_b2, out, hbuf);
  flumen_wshuf<<<1024, 512, 0, stream>>>(w_hh, Wshuf);
  flumen_convaug<<<64, 512, 0, stream>>>(w_ih, bias, Waug);
  flumen_convx<<<2048, 512, 0, stream>>>(rnn_input, Xhat);
  flumen_lstm<<<32, 512, 0, stream>>>(Wshuf, Waug, Xhat, hbuf, flags, out);
}